// Round 1
// baseline (995.639 us; speedup 1.0000x reference)
//
#include <hip/hip_runtime.h>
#include <hip/hip_bf16.h>
#include <cstdint>

#define EPS 1e-5f
#define NEG 0.1f

typedef float f4 __attribute__((ext_vector_type(4)));

// geometry
constexpr int B_  = 4,  CIN = 64, H0 = 192, W0 = 192;
constexpr int C_  = 128, H_ = 96, W_ = 96;
constexpr int HW_ = H_ * W_;      // 9216
constexpr int HW0 = H0 * W0;      // 36864

// ---------------------------------------------------------------------------
// Weight transpose: w[O][KK] -> wt[KK][Opad] (zero-padded in O)
// ---------------------------------------------------------------------------
__global__ void k_wtrans(const float* __restrict__ w, float* __restrict__ wt,
                         int O, int KK, int Opad) {
  int t = blockIdx.x * 256 + threadIdx.x;
  if (t >= KK * Opad) return;
  int o = t % Opad, kk = t / Opad;
  wt[t] = (o < O) ? w[(size_t)o * KK + kk] : 0.f;
}

// ---------------------------------------------------------------------------
// K1: conv3x3 stride2 pad1 (64->128) + BN + LReLU.  x[4,64,192,192] -> t1[4,128,96,96]
// block (96,2), thread computes 8 output channels for one (i,j)
// ---------------------------------------------------------------------------
__global__ __launch_bounds__(192)
void k_conv1(const float* __restrict__ x, const float* __restrict__ wt,
             const float* __restrict__ bnp, float* __restrict__ t1) {
  int j = threadIdx.x;
  int i = blockIdx.x * 2 + threadIdx.y;
  int o0 = blockIdx.y * 8;
  int b = blockIdx.z;
  float acc[8] = {0,0,0,0,0,0,0,0};
  const float* xb = x + (size_t)b * CIN * HW0;
  for (int c = 0; c < CIN; ++c) {
    const float* xc = xb + (size_t)c * HW0;
    float v[9];
#pragma unroll
    for (int di = 0; di < 3; ++di) {
      int iy = 2 * i - 1 + di;
      bool okr = (unsigned)iy < (unsigned)H0;
#pragma unroll
      for (int dj = 0; dj < 3; ++dj) {
        int ix = 2 * j - 1 + dj;
        v[di*3+dj] = (okr && (unsigned)ix < (unsigned)W0) ? xc[iy * W0 + ix] : 0.f;
      }
    }
#pragma unroll
    for (int k = 0; k < 9; ++k) {
      const float* wr = wt + (size_t)(c*9+k) * 128 + o0;
      f4 wa = *(const f4*)wr, wb = *(const f4*)(wr + 4);
#pragma unroll
      for (int t = 0; t < 4; ++t) { acc[t] += v[k]*wa[t]; acc[4+t] += v[k]*wb[t]; }
    }
  }
#pragma unroll
  for (int oo = 0; oo < 8; ++oo) {
    int o = o0 + oo;
    float inv = bnp[o] * rsqrtf(bnp[384+o] + EPS);
    float r = acc[oo]*inv + (bnp[128+o] - bnp[256+o]*inv);
    r = r >= 0.f ? r : NEG * r;
    t1[((size_t)(b*C_+o)*H_ + i)*W_ + j] = r;
  }
}

// ---------------------------------------------------------------------------
// K2: conv3x3 s1 p1 (128->128)+BN  +  conv1x1 s2 (64->128)+BN shortcut, add, LReLU
// t1,x -> t3
// ---------------------------------------------------------------------------
__global__ __launch_bounds__(192)
void k_conv2(const float* __restrict__ t1, const float* __restrict__ x,
             const float* __restrict__ wt2, const float* __restrict__ wtrs,
             const float* __restrict__ bn2p, const float* __restrict__ bnsp,
             float* __restrict__ t3) {
  int j = threadIdx.x;
  int i = blockIdx.x * 2 + threadIdx.y;
  int o0 = blockIdx.y * 8;
  int b = blockIdx.z;
  float acc[8] = {0,0,0,0,0,0,0,0};
  const float* tb = t1 + (size_t)b * C_ * HW_;
  for (int c = 0; c < C_; ++c) {
    const float* tc = tb + (size_t)c * HW_;
    float v[9];
#pragma unroll
    for (int di = 0; di < 3; ++di) {
      int iy = i - 1 + di;
      bool okr = (unsigned)iy < (unsigned)H_;
#pragma unroll
      for (int dj = 0; dj < 3; ++dj) {
        int ix = j - 1 + dj;
        v[di*3+dj] = (okr && (unsigned)ix < (unsigned)W_) ? tc[iy * W_ + ix] : 0.f;
      }
    }
#pragma unroll
    for (int k = 0; k < 9; ++k) {
      const float* wr = wt2 + (size_t)(c*9+k) * 128 + o0;
      f4 wa = *(const f4*)wr, wb = *(const f4*)(wr + 4);
#pragma unroll
      for (int t = 0; t < 4; ++t) { acc[t] += v[k]*wa[t]; acc[4+t] += v[k]*wb[t]; }
    }
  }
  float accs[8] = {0,0,0,0,0,0,0,0};
  const float* xb = x + (size_t)b * CIN * HW0 + (size_t)(2*i) * W0 + 2*j;
  for (int c = 0; c < CIN; ++c) {
    float v = xb[(size_t)c * HW0];
    const float* wr = wtrs + (size_t)c * 128 + o0;
    f4 wa = *(const f4*)wr, wb = *(const f4*)(wr + 4);
#pragma unroll
    for (int t = 0; t < 4; ++t) { accs[t] += v*wa[t]; accs[4+t] += v*wb[t]; }
  }
#pragma unroll
  for (int oo = 0; oo < 8; ++oo) {
    int o = o0 + oo;
    float i2 = bn2p[o] * rsqrtf(bn2p[384+o] + EPS);
    float r  = acc[oo]*i2 + (bn2p[128+o] - bn2p[256+o]*i2);
    float is = bnsp[o] * rsqrtf(bnsp[384+o] + EPS);
    float s  = accs[oo]*is + (bnsp[128+o] - bnsp[256+o]*is);
    float h = r + s;
    h = h >= 0.f ? h : NEG * h;
    t3[((size_t)(b*C_+o)*H_ + i)*W_ + j] = h;
  }
}

// ---------------------------------------------------------------------------
// K2b: transpose t3 [b,128,9216] -> channel-last t3cl [(b*2+g)*9216 + p][64]
// ---------------------------------------------------------------------------
__global__ __launch_bounds__(256)
void k_t3cl(const float* __restrict__ t3, float* __restrict__ t3cl) {
  __shared__ float tile[64][65];
  int tx = threadIdx.x;            // 0..63
  int ty = threadIdx.y;            // 0..3
  int p0 = blockIdx.x * 64;
  int g = blockIdx.y;
  int b = blockIdx.z;
  const float* src = t3 + (size_t)(b*C_ + g*64) * HW_;
#pragma unroll
  for (int r = 0; r < 16; ++r) {
    int ch = r * 4 + ty;
    tile[ch][tx] = src[(size_t)ch * HW_ + p0 + tx];
  }
  __syncthreads();
  float* dst = t3cl + ((size_t)(b*2+g) * HW_ + p0) * 64;
#pragma unroll
  for (int r = 0; r < 16; ++r) {
    int pp = r * 4 + ty;
    dst[(size_t)pp * 64 + tx] = tile[tx][pp];
  }
}

// ---------------------------------------------------------------------------
// K3: conv3x3 s1 p1 (128->54) + bias -> off[4,54,96,96]  (Opad=64 weights)
// ---------------------------------------------------------------------------
__global__ __launch_bounds__(192)
void k_convoff(const float* __restrict__ t3, const float* __restrict__ wt,
               const float* __restrict__ boff, float* __restrict__ offb) {
  int j = threadIdx.x;
  int i = blockIdx.x * 2 + threadIdx.y;
  int o0 = blockIdx.y * 8;
  int b = blockIdx.z;
  float acc[8] = {0,0,0,0,0,0,0,0};
  const float* tb = t3 + (size_t)b * C_ * HW_;
  for (int c = 0; c < C_; ++c) {
    const float* tc = tb + (size_t)c * HW_;
    float v[9];
#pragma unroll
    for (int di = 0; di < 3; ++di) {
      int iy = i - 1 + di;
      bool okr = (unsigned)iy < (unsigned)H_;
#pragma unroll
      for (int dj = 0; dj < 3; ++dj) {
        int ix = j - 1 + dj;
        v[di*3+dj] = (okr && (unsigned)ix < (unsigned)W_) ? tc[iy * W_ + ix] : 0.f;
      }
    }
#pragma unroll
    for (int k = 0; k < 9; ++k) {
      const float* wr = wt + (size_t)(c*9+k) * 64 + o0;
      f4 wa = *(const f4*)wr, wb = *(const f4*)(wr + 4);
#pragma unroll
      for (int t = 0; t < 4; ++t) { acc[t] += v[k]*wa[t]; acc[4+t] += v[k]*wb[t]; }
    }
  }
#pragma unroll
  for (int oo = 0; oo < 8; ++oo) {
    int o = o0 + oo;
    if (o < 54)
      offb[((size_t)(b*54+o)*H_ + i)*W_ + j] = acc[oo] + boff[o];
  }
}

// ---------------------------------------------------------------------------
// K4: DCNv2 sample + contract + bias + BN + LReLU -> t4
// block 128 threads, 8 pixels per block (one row segment).
// val LDS layout: [pix][kk] with kk = (g*64+c)*9 + k   (matches wt_dcn rows)
// ---------------------------------------------------------------------------
__global__ __launch_bounds__(128)
void k_dcn(const float* __restrict__ t3cl, const float* __restrict__ offb,
           const float* __restrict__ wt, const float* __restrict__ bdcn,
           const float* __restrict__ bnp, float* __restrict__ t4) {
  __shared__ float val[8 * 1152];
  int tid = threadIdx.x;
  int j0 = blockIdx.x * 8;
  int i = blockIdx.y;
  int b = blockIdx.z;
  // ---- sampling: 8*1152 samples, 72 per thread ----
  {
    int q = tid, pix = 0;
    for (int it = 0; it < 72; ++it) {
      int gk = q >> 6, c = q & 63;
      int g = gk / 9, k = gk - 9 * g;
      int ky = k / 3, kx = k - 3 * ky;
      int j = j0 + pix;
      const float* ob = offb + (size_t)b * 54 * HW_ + i * W_ + j;
      float dy = ob[(size_t)gk * HW_];
      float dx = ob[(size_t)(18 + gk) * HW_];
      float ml = ob[(size_t)(36 + gk) * HW_];
      float mk = 1.f / (1.f + __expf(-ml));
      float py = (float)(i - 1 + ky) + dy;
      float px = (float)(j - 1 + kx) + dx;
      float fy = floorf(py), fx = floorf(px);
      float wy = py - fy, wx = px - fx;
      int y0 = (int)fy, x0 = (int)fx;
      const float* tb = t3cl + ((size_t)(b*2+g) * HW_) * 64 + c;
      float v00 = 0.f, v01 = 0.f, v10 = 0.f, v11 = 0.f;
      if ((unsigned)y0 < 96u) {
        if ((unsigned)x0       < 96u) v00 = tb[(y0*96 + x0    ) * 64];
        if ((unsigned)(x0 + 1) < 96u) v01 = tb[(y0*96 + x0 + 1) * 64];
      }
      if ((unsigned)(y0 + 1) < 96u) {
        if ((unsigned)x0       < 96u) v10 = tb[((y0+1)*96 + x0    ) * 64];
        if ((unsigned)(x0 + 1) < 96u) v11 = tb[((y0+1)*96 + x0 + 1) * 64];
      }
      float vv = ((v00*(1.f-wx) + v01*wx)*(1.f-wy) +
                  (v10*(1.f-wx) + v11*wx)*wy) * mk;
      val[pix * 1152 + (g*64 + c) * 9 + k] = vv;
      q += 128; if (q >= 1152) { q -= 1152; ++pix; }
    }
  }
  __syncthreads();
  // ---- contraction: thread tile 4 o x 2 pix ----
  int tx = tid & 31, ty = tid >> 5;     // tx: o-tile, ty: 0..3 pix-tile
  int o0 = tx * 4, p0 = ty * 2;
  float acc[4][2] = {{0,0},{0,0},{0,0},{0,0}};
  for (int q = 0; q < 1152; q += 4) {
    f4 wv[4];
#pragma unroll
    for (int dq = 0; dq < 4; ++dq)
      wv[dq] = *(const f4*)(wt + (size_t)(q + dq) * 128 + o0);
    f4 va = *(const f4*)(val + p0 * 1152 + q);
    f4 vb = *(const f4*)(val + (p0 + 1) * 1152 + q);
#pragma unroll
    for (int dq = 0; dq < 4; ++dq)
#pragma unroll
      for (int oo = 0; oo < 4; ++oo) {
        acc[oo][0] += wv[dq][oo] * va[dq];
        acc[oo][1] += wv[dq][oo] * vb[dq];
      }
  }
#pragma unroll
  for (int oo = 0; oo < 4; ++oo) {
    int o = o0 + oo;
    float inv = bnp[o] * rsqrtf(bnp[384+o] + EPS);
    float bb = bnp[128+o] - bnp[256+o] * inv;
    float bd = bdcn[o];
#pragma unroll
    for (int pp = 0; pp < 2; ++pp) {
      float r = (acc[oo][pp] + bd) * inv + bb;
      r = r >= 0.f ? r : NEG * r;
      t4[((size_t)(b*C_+o)*H_ + i)*W_ + (j0 + p0 + pp)] = r;
    }
  }
}

// ---------------------------------------------------------------------------
// K5: conv1x1 (128->128)+BN+LReLU  +  conv1x1 s2 (64->128)+BN residual -> out
// ---------------------------------------------------------------------------
__global__ __launch_bounds__(192)
void k_final(const float* __restrict__ t4, const float* __restrict__ x,
             const float* __restrict__ wtc2, const float* __restrict__ wtds,
             const float* __restrict__ bn2p, const float* __restrict__ bndsp,
             float* __restrict__ outp) {
  int j = threadIdx.x;
  int i = blockIdx.x * 2 + threadIdx.y;
  int o0 = blockIdx.y * 8;
  int b = blockIdx.z;
  float acc[8]  = {0,0,0,0,0,0,0,0};
  float accd[8] = {0,0,0,0,0,0,0,0};
  const float* tb = t4 + (size_t)b * C_ * HW_ + (size_t)i * W_ + j;
  for (int c = 0; c < C_; ++c) {
    float v = tb[(size_t)c * HW_];
    const float* wr = wtc2 + (size_t)c * 128 + o0;
    f4 wa = *(const f4*)wr, wb = *(const f4*)(wr + 4);
#pragma unroll
    for (int t = 0; t < 4; ++t) { acc[t] += v*wa[t]; acc[4+t] += v*wb[t]; }
  }
  const float* xb = x + (size_t)b * CIN * HW0 + (size_t)(2*i) * W0 + 2*j;
  for (int c = 0; c < CIN; ++c) {
    float v = xb[(size_t)c * HW0];
    const float* wr = wtds + (size_t)c * 128 + o0;
    f4 wa = *(const f4*)wr, wb = *(const f4*)(wr + 4);
#pragma unroll
    for (int t = 0; t < 4; ++t) { accd[t] += v*wa[t]; accd[4+t] += v*wb[t]; }
  }
#pragma unroll
  for (int oo = 0; oo < 8; ++oo) {
    int o = o0 + oo;
    float i2 = bn2p[o] * rsqrtf(bn2p[384+o] + EPS);
    float h  = acc[oo]*i2 + (bn2p[128+o] - bn2p[256+o]*i2);
    h = h >= 0.f ? h : NEG * h;
    float id = bndsp[o] * rsqrtf(bndsp[384+o] + EPS);
    float res = accd[oo]*id + (bndsp[128+o] - bndsp[256+o]*id);
    outp[((size_t)(b*C_+o)*H_ + i)*W_ + j] = res + h;
  }
}

// ---------------------------------------------------------------------------
extern "C" void kernel_launch(void* const* d_in, const int* in_sizes, int n_in,
                              void* d_out, int out_size, void* d_ws, size_t ws_size,
                              hipStream_t stream) {
  const float* x     = (const float*)d_in[0];
  const float* w_r1  = (const float*)d_in[1];
  const float* bn_r1 = (const float*)d_in[2];
  const float* w_r2  = (const float*)d_in[3];
  const float* bn_r2 = (const float*)d_in[4];
  const float* w_rs  = (const float*)d_in[5];
  const float* bn_rs = (const float*)d_in[6];
  const float* w_off = (const float*)d_in[7];
  const float* b_off = (const float*)d_in[8];
  const float* w_dcn = (const float*)d_in[9];
  const float* b_dcn = (const float*)d_in[10];
  const float* bn1   = (const float*)d_in[11];
  const float* w_c2  = (const float*)d_in[12];
  const float* bn2   = (const float*)d_in[13];
  const float* w_ds  = (const float*)d_in[14];
  const float* bn_ds = (const float*)d_in[15];
  float* out = (float*)d_out;

  float* ws = (float*)d_ws;
  float* A     = ws;                 // t1, later t3cl
  float* Bf    = A + 4718592;        // t3, later t4
  float* offb  = Bf + 4718592;
  float* wt_r1 = offb + 1990656;
  float* wt_r2 = wt_r1 + 73728;
  float* wt_rs = wt_r2 + 147456;
  float* wt_off= wt_rs + 8192;
  float* wt_dcn= wt_off + 73728;
  float* wt_c2 = wt_dcn + 147456;
  float* wt_ds = wt_c2 + 16384;

  auto T = [&](const float* w, float* wt, int O, int KK, int Opad) {
    int n = KK * Opad;
    k_wtrans<<<dim3((n + 255) / 256), dim3(256), 0, stream>>>(w, wt, O, KK, Opad);
  };
  T(w_r1,  wt_r1, 128, 576, 128);
  T(w_r2,  wt_r2, 128, 1152, 128);
  T(w_rs,  wt_rs, 128, 64, 128);
  T(w_off, wt_off, 54, 1152, 64);
  T(w_dcn, wt_dcn, 128, 1152, 128);
  T(w_c2,  wt_c2, 128, 128, 128);
  T(w_ds,  wt_ds, 128, 64, 128);

  k_conv1 <<<dim3(48,16,4), dim3(96,2), 0, stream>>>(x, wt_r1, bn_r1, A);
  k_conv2 <<<dim3(48,16,4), dim3(96,2), 0, stream>>>(A, x, wt_r2, wt_rs, bn_r2, bn_rs, Bf);
  k_t3cl  <<<dim3(144,2,4), dim3(64,4), 0, stream>>>(Bf, A);
  k_convoff<<<dim3(48,8,4), dim3(96,2), 0, stream>>>(Bf, wt_off, b_off, offb);
  k_dcn   <<<dim3(12,96,4), dim3(128), 0, stream>>>(A, offb, wt_dcn, b_dcn, bn1, Bf);
  k_final <<<dim3(48,16,4), dim3(96,2), 0, stream>>>(Bf, x, wt_c2, wt_ds, bn2, bn_ds, out);
}

// Round 2
// 654.428 us; speedup vs baseline: 1.5214x; 1.5214x over previous
//
#include <hip/hip_runtime.h>
#include <hip/hip_bf16.h>
#include <cstdint>

#define EPS 1e-5f
#define NEG 0.1f

typedef float f4 __attribute__((ext_vector_type(4)));
using bfrag = __attribute__((ext_vector_type(8))) short;   // 8 bf16 (4 VGPR)
using f32x4 = __attribute__((ext_vector_type(4))) float;

// geometry
constexpr int B_  = 4,  CIN = 64, H0 = 192, W0 = 192;
constexpr int C_  = 128, H_ = 96, W_ = 96;
constexpr int HW_ = H_ * W_;      // 9216
constexpr int HW0 = H0 * W0;      // 36864
constexpr int PAD_CL = 6208;      // 97*64 front pad for t3cl negative-base gathers

__device__ __forceinline__ unsigned short f2bf(float f) {
  unsigned u = __builtin_bit_cast(unsigned, f);
  u += 0x7fffu + ((u >> 16) & 1u);
  return (unsigned short)(u >> 16);
}
__device__ __forceinline__ float bf2f(unsigned short s) {
  return __builtin_bit_cast(float, (unsigned)s << 16);
}

// ---------------------------------------------------------------------------
// Weight transpose: w[O][KK] -> wt[KK][Opad] (zero-padded in O)
// ---------------------------------------------------------------------------
__global__ void k_wtrans(const float* __restrict__ w, float* __restrict__ wt,
                         int O, int KK, int Opad) {
  int t = blockIdx.x * 256 + threadIdx.x;
  if (t >= KK * Opad) return;
  int o = t % Opad, kk = t / Opad;
  wt[t] = (o < O) ? w[(size_t)o * KK + kk] : 0.f;
}

// wpack: w_dcn[O=128][KK=1152] fp32 -> bf16 [s=KK/32][o][32] fragment-contiguous
__global__ __launch_bounds__(256)
void k_wpack(const float* __restrict__ w, unsigned short* __restrict__ wp) {
  int idx = blockIdx.x * 256 + threadIdx.x;        // 147456 total
  int e = idx & 31, o = (idx >> 5) & 127, s = idx >> 12;
  wp[idx] = f2bf(w[(size_t)o * 1152 + s * 32 + e]);
}

// ---------------------------------------------------------------------------
// K1: conv3x3 stride2 pad1 (64->128) + BN + LReLU.
// ---------------------------------------------------------------------------
__global__ __launch_bounds__(192)
void k_conv1(const float* __restrict__ x, const float* __restrict__ wt,
             const float* __restrict__ bnp, float* __restrict__ t1) {
  int j = threadIdx.x;
  int i = blockIdx.x * 2 + threadIdx.y;
  int o0 = blockIdx.y * 8;
  int b = blockIdx.z;
  float acc[8] = {0,0,0,0,0,0,0,0};
  const float* xb = x + (size_t)b * CIN * HW0;
  for (int c = 0; c < CIN; ++c) {
    const float* xc = xb + (size_t)c * HW0;
    float v[9];
#pragma unroll
    for (int di = 0; di < 3; ++di) {
      int iy = 2 * i - 1 + di;
      bool okr = (unsigned)iy < (unsigned)H0;
#pragma unroll
      for (int dj = 0; dj < 3; ++dj) {
        int ix = 2 * j - 1 + dj;
        v[di*3+dj] = (okr && (unsigned)ix < (unsigned)W0) ? xc[iy * W0 + ix] : 0.f;
      }
    }
#pragma unroll
    for (int k = 0; k < 9; ++k) {
      const float* wr = wt + (size_t)(c*9+k) * 128 + o0;
      f4 wa = *(const f4*)wr, wb = *(const f4*)(wr + 4);
#pragma unroll
      for (int t = 0; t < 4; ++t) { acc[t] += v[k]*wa[t]; acc[4+t] += v[k]*wb[t]; }
    }
  }
#pragma unroll
  for (int oo = 0; oo < 8; ++oo) {
    int o = o0 + oo;
    float inv = bnp[o] * rsqrtf(bnp[384+o] + EPS);
    float r = acc[oo]*inv + (bnp[128+o] - bnp[256+o]*inv);
    r = r >= 0.f ? r : NEG * r;
    t1[((size_t)(b*C_+o)*H_ + i)*W_ + j] = r;
  }
}

// ---------------------------------------------------------------------------
// K2: conv3x3 s1 p1 (128->128)+BN + conv1x1 s2 (64->128)+BN shortcut, add, LReLU
// ---------------------------------------------------------------------------
__global__ __launch_bounds__(192)
void k_conv2(const float* __restrict__ t1, const float* __restrict__ x,
             const float* __restrict__ wt2, const float* __restrict__ wtrs,
             const float* __restrict__ bn2p, const float* __restrict__ bnsp,
             float* __restrict__ t3) {
  int j = threadIdx.x;
  int i = blockIdx.x * 2 + threadIdx.y;
  int o0 = blockIdx.y * 8;
  int b = blockIdx.z;
  float acc[8] = {0,0,0,0,0,0,0,0};
  const float* tb = t1 + (size_t)b * C_ * HW_;
  for (int c = 0; c < C_; ++c) {
    const float* tc = tb + (size_t)c * HW_;
    float v[9];
#pragma unroll
    for (int di = 0; di < 3; ++di) {
      int iy = i - 1 + di;
      bool okr = (unsigned)iy < (unsigned)H_;
#pragma unroll
      for (int dj = 0; dj < 3; ++dj) {
        int ix = j - 1 + dj;
        v[di*3+dj] = (okr && (unsigned)ix < (unsigned)W_) ? tc[iy * W_ + ix] : 0.f;
      }
    }
#pragma unroll
    for (int k = 0; k < 9; ++k) {
      const float* wr = wt2 + (size_t)(c*9+k) * 128 + o0;
      f4 wa = *(const f4*)wr, wb = *(const f4*)(wr + 4);
#pragma unroll
      for (int t = 0; t < 4; ++t) { acc[t] += v[k]*wa[t]; acc[4+t] += v[k]*wb[t]; }
    }
  }
  float accs[8] = {0,0,0,0,0,0,0,0};
  const float* xb = x + (size_t)b * CIN * HW0 + (size_t)(2*i) * W0 + 2*j;
  for (int c = 0; c < CIN; ++c) {
    float v = xb[(size_t)c * HW0];
    const float* wr = wtrs + (size_t)c * 128 + o0;
    f4 wa = *(const f4*)wr, wb = *(const f4*)(wr + 4);
#pragma unroll
    for (int t = 0; t < 4; ++t) { accs[t] += v*wa[t]; accs[4+t] += v*wb[t]; }
  }
#pragma unroll
  for (int oo = 0; oo < 8; ++oo) {
    int o = o0 + oo;
    float i2 = bn2p[o] * rsqrtf(bn2p[384+o] + EPS);
    float r  = acc[oo]*i2 + (bn2p[128+o] - bn2p[256+o]*i2);
    float is = bnsp[o] * rsqrtf(bnsp[384+o] + EPS);
    float s  = accs[oo]*is + (bnsp[128+o] - bnsp[256+o]*is);
    float h = r + s;
    h = h >= 0.f ? h : NEG * h;
    t3[((size_t)(b*C_+o)*H_ + i)*W_ + j] = h;
  }
}

// ---------------------------------------------------------------------------
// K2b: transpose t3 [b,128,9216] -> channel-last t3cl [(b*2+g)*9216 + p][64]
// ---------------------------------------------------------------------------
__global__ __launch_bounds__(256)
void k_t3cl(const float* __restrict__ t3, float* __restrict__ t3cl) {
  __shared__ float tile[64][65];
  int tx = threadIdx.x;            // 0..63
  int ty = threadIdx.y;            // 0..3
  int p0 = blockIdx.x * 64;
  int g = blockIdx.y;
  int b = blockIdx.z;
  const float* src = t3 + (size_t)(b*C_ + g*64) * HW_;
#pragma unroll
  for (int r = 0; r < 16; ++r) {
    int ch = r * 4 + ty;
    tile[ch][tx] = src[(size_t)ch * HW_ + p0 + tx];
  }
  __syncthreads();
  float* dst = t3cl + ((size_t)(b*2+g) * HW_ + p0) * 64;
#pragma unroll
  for (int r = 0; r < 16; ++r) {
    int pp = r * 4 + ty;
    dst[(size_t)pp * 64 + tx] = tile[tx][pp];
  }
}

// ---------------------------------------------------------------------------
// K3: conv3x3 s1 p1 (128->54) + bias -> off[4,54,96,96]  (Opad=64 weights)
// ---------------------------------------------------------------------------
__global__ __launch_bounds__(192)
void k_convoff(const float* __restrict__ t3, const float* __restrict__ wt,
               const float* __restrict__ boff, float* __restrict__ offb) {
  int j = threadIdx.x;
  int i = blockIdx.x * 2 + threadIdx.y;
  int o0 = blockIdx.y * 8;
  int b = blockIdx.z;
  float acc[8] = {0,0,0,0,0,0,0,0};
  const float* tb = t3 + (size_t)b * C_ * HW_;
  for (int c = 0; c < C_; ++c) {
    const float* tc = tb + (size_t)c * HW_;
    float v[9];
#pragma unroll
    for (int di = 0; di < 3; ++di) {
      int iy = i - 1 + di;
      bool okr = (unsigned)iy < (unsigned)H_;
#pragma unroll
      for (int dj = 0; dj < 3; ++dj) {
        int ix = j - 1 + dj;
        v[di*3+dj] = (okr && (unsigned)ix < (unsigned)W_) ? tc[iy * W_ + ix] : 0.f;
      }
    }
#pragma unroll
    for (int k = 0; k < 9; ++k) {
      const float* wr = wt + (size_t)(c*9+k) * 64 + o0;
      f4 wa = *(const f4*)wr, wb = *(const f4*)(wr + 4);
#pragma unroll
      for (int t = 0; t < 4; ++t) { acc[t] += v[k]*wa[t]; acc[4+t] += v[k]*wb[t]; }
    }
  }
#pragma unroll
  for (int oo = 0; oo < 8; ++oo) {
    int o = o0 + oo;
    if (o < 54)
      offb[((size_t)(b*54+o)*H_ + i)*W_ + j] = acc[oo] + boff[o];
  }
}

// ---------------------------------------------------------------------------
// K4: DCNv2 — per-point precompute (LDS) -> coalesced bilinear gather ->
//     bf16 val tile -> MFMA contraction -> BN+LReLU -> t4
// block 256 threads (4 waves), 32 pixels (one row segment), K=1152
// ---------------------------------------------------------------------------
constexpr int VSTR = 1160;   // val row stride in bf16 elems (16B-aligned, bank-spread)

__global__ __launch_bounds__(256)
void k_dcn(const float* __restrict__ t3cl,    // padded base: real data at +PAD_CL
           const float* __restrict__ offb,
           const unsigned short* __restrict__ wpack,
           const float* __restrict__ bdcn, const float* __restrict__ bnp,
           float* __restrict__ t4) {
  __shared__ unsigned short val[32 * VSTR];   // 74240 B
  __shared__ ushort4 pre_w[576];              // 4608 B
  __shared__ int     pre_b[576];              // 2304 B

  int tid = threadIdx.x;
  int j0 = blockIdx.x * 32;
  int i  = blockIdx.y;
  int b  = blockIdx.z;

  // ---- phase 0: per-point offset/mask/bilinear-weight precompute ----
  for (int t = tid; t < 576; t += 256) {
    int pix = t / 18, gk = t - pix * 18;
    int g = gk / 9, k = gk - 9 * g;
    int ky = k / 3, kx = k - 3 * ky;
    int j = j0 + pix;
    const float* ob = offb + ((size_t)b * 54 + gk) * HW_ + i * W_ + j;
    float dy = ob[0];
    float dx = ob[(size_t)18 * HW_];
    float ml = ob[(size_t)36 * HW_];
    float mk = 1.f / (1.f + __expf(-ml));
    float py = (float)(i - 1 + ky) + dy;
    float px = (float)(j - 1 + kx) + dx;
    float fy = floorf(py), fx = floorf(px);
    float wy = py - fy, wx = px - fx;
    int y0 = (int)fy, x0 = (int)fx;
    bool yv0 = (unsigned)y0 < 96u, yv1 = (unsigned)(y0 + 1) < 96u;
    bool xv0 = (unsigned)x0 < 96u, xv1 = (unsigned)(x0 + 1) < 96u;
    float w00 = (yv0 && xv0) ? (1.f - wy) * (1.f - wx) * mk : 0.f;
    float w01 = (yv0 && xv1) ? (1.f - wy) * wx * mk : 0.f;
    float w10 = (yv1 && xv0) ? wy * (1.f - wx) * mk : 0.f;
    float w11 = (yv1 && xv1) ? wy * wx * mk : 0.f;
    int yb = min(max(y0, -1), 95), xb = min(max(x0, -1), 95);
    pre_b[t] = yb * 96 + xb;
    pre_w[t] = make_ushort4(f2bf(w00), f2bf(w01), f2bf(w10), f2bf(w11));
  }
  __syncthreads();

  // ---- phase 1: gather 32x1152 samples, write bf16 val tile ----
  {
    int c = tid & 63;
    int s = tid >> 6;
    const float* img0 = t3cl + PAD_CL + (size_t)(b * 2) * HW_ * 64 + c;
    for (int t = s; t < 576; t += 4) {
      int pix = t / 18, gk = t - pix * 18;
      int g = gk / 9, k = gk - 9 * g;
      ushort4 w4 = pre_w[t];
      int base = pre_b[t];
      const float* tb = img0 + ((size_t)g * HW_ + base) * 64;
      float v00 = tb[0];
      float v01 = tb[64];
      float v10 = tb[96 * 64];
      float v11 = tb[97 * 64];
      float vv = bf2f(w4.x) * v00 + bf2f(w4.y) * v01 +
                 bf2f(w4.z) * v10 + bf2f(w4.w) * v11;
      val[pix * VSTR + (g * 64 + c) * 9 + k] = f2bf(vv);
    }
  }
  __syncthreads();

  // ---- phase 2: MFMA contraction: out[32 pix][128 o] over K=1152 ----
  int lane = tid & 63, wv = tid >> 6;
  int lr = lane & 15, lq = lane >> 4;          // lq 0..3
  int ob = wv * 32;
  f32x4 acc[2][2] = {};
  for (int s = 0; s < 36; ++s) {
    bfrag a0 = *(const bfrag*)&val[lr * VSTR + 32 * s + 8 * lq];
    bfrag a1 = *(const bfrag*)&val[(16 + lr) * VSTR + 32 * s + 8 * lq];
    bfrag b0 = *(const bfrag*)&wpack[(size_t)(s * 128 + ob + lr) * 32 + 8 * lq];
    bfrag b1 = *(const bfrag*)&wpack[(size_t)(s * 128 + ob + 16 + lr) * 32 + 8 * lq];
    acc[0][0] = __builtin_amdgcn_mfma_f32_16x16x32_bf16(a0, b0, acc[0][0], 0, 0, 0);
    acc[0][1] = __builtin_amdgcn_mfma_f32_16x16x32_bf16(a0, b1, acc[0][1], 0, 0, 0);
    acc[1][0] = __builtin_amdgcn_mfma_f32_16x16x32_bf16(a1, b0, acc[1][0], 0, 0, 0);
    acc[1][1] = __builtin_amdgcn_mfma_f32_16x16x32_bf16(a1, b1, acc[1][1], 0, 0, 0);
  }
  __syncthreads();

  // ---- epilogue: stage [o][pix] in LDS, BN+LReLU, coalesced store ----
  float* ol = (float*)val;                     // reuse (needs 128*33*4 = 16.9KB)
#pragma unroll
  for (int mf = 0; mf < 2; ++mf)
#pragma unroll
    for (int nf = 0; nf < 2; ++nf)
#pragma unroll
      for (int jj = 0; jj < 4; ++jj) {
        int o = ob + nf * 16 + lr;
        int pix = mf * 16 + 4 * lq + jj;
        ol[o * 33 + pix] = acc[mf][nf][jj];
      }
  __syncthreads();
#pragma unroll
  for (int r = 0; r < 16; ++r) {
    int idx = r * 256 + tid;
    int o = idx >> 5, pix = idx & 31;
    float a = ol[o * 33 + pix];
    float inv = bnp[o] * rsqrtf(bnp[384 + o] + EPS);
    float r2 = (a + bdcn[o]) * inv + (bnp[128 + o] - bnp[256 + o] * inv);
    r2 = r2 >= 0.f ? r2 : NEG * r2;
    t4[((size_t)(b * C_ + o) * H_ + i) * W_ + j0 + pix] = r2;
  }
}

// ---------------------------------------------------------------------------
// K5: conv1x1 (128->128)+BN+LReLU  +  conv1x1 s2 (64->128)+BN residual -> out
// ---------------------------------------------------------------------------
__global__ __launch_bounds__(192)
void k_final(const float* __restrict__ t4, const float* __restrict__ x,
             const float* __restrict__ wtc2, const float* __restrict__ wtds,
             const float* __restrict__ bn2p, const float* __restrict__ bndsp,
             float* __restrict__ outp) {
  int j = threadIdx.x;
  int i = blockIdx.x * 2 + threadIdx.y;
  int o0 = blockIdx.y * 8;
  int b = blockIdx.z;
  float acc[8]  = {0,0,0,0,0,0,0,0};
  float accd[8] = {0,0,0,0,0,0,0,0};
  const float* tb = t4 + (size_t)b * C_ * HW_ + (size_t)i * W_ + j;
  for (int c = 0; c < C_; ++c) {
    float v = tb[(size_t)c * HW_];
    const float* wr = wtc2 + (size_t)c * 128 + o0;
    f4 wa = *(const f4*)wr, wb = *(const f4*)(wr + 4);
#pragma unroll
    for (int t = 0; t < 4; ++t) { acc[t] += v*wa[t]; acc[4+t] += v*wb[t]; }
  }
  const float* xb = x + (size_t)b * CIN * HW0 + (size_t)(2*i) * W0 + 2*j;
  for (int c = 0; c < CIN; ++c) {
    float v = xb[(size_t)c * HW0];
    const float* wr = wtds + (size_t)c * 128 + o0;
    f4 wa = *(const f4*)wr, wb = *(const f4*)(wr + 4);
#pragma unroll
    for (int t = 0; t < 4; ++t) { accd[t] += v*wa[t]; accd[4+t] += v*wb[t]; }
  }
#pragma unroll
  for (int oo = 0; oo < 8; ++oo) {
    int o = o0 + oo;
    float i2 = bn2p[o] * rsqrtf(bn2p[384+o] + EPS);
    float h  = acc[oo]*i2 + (bn2p[128+o] - bn2p[256+o]*i2);
    h = h >= 0.f ? h : NEG * h;
    float id = bndsp[o] * rsqrtf(bndsp[384+o] + EPS);
    float res = accd[oo]*id + (bndsp[128+o] - bndsp[256+o]*id);
    outp[((size_t)(b*C_+o)*H_ + i)*W_ + j] = res + h;
  }
}

// ---------------------------------------------------------------------------
extern "C" void kernel_launch(void* const* d_in, const int* in_sizes, int n_in,
                              void* d_out, int out_size, void* d_ws, size_t ws_size,
                              hipStream_t stream) {
  const float* x     = (const float*)d_in[0];
  const float* w_r1  = (const float*)d_in[1];
  const float* bn_r1 = (const float*)d_in[2];
  const float* w_r2  = (const float*)d_in[3];
  const float* bn_r2 = (const float*)d_in[4];
  const float* w_rs  = (const float*)d_in[5];
  const float* bn_rs = (const float*)d_in[6];
  const float* w_off = (const float*)d_in[7];
  const float* b_off = (const float*)d_in[8];
  const float* w_dcn = (const float*)d_in[9];
  const float* b_dcn = (const float*)d_in[10];
  const float* bn1   = (const float*)d_in[11];
  const float* w_c2  = (const float*)d_in[12];
  const float* bn2   = (const float*)d_in[13];
  const float* w_ds  = (const float*)d_in[14];
  const float* bn_ds = (const float*)d_in[15];
  float* out = (float*)d_out;

  float* ws = (float*)d_ws;
  float* A     = ws;                 // t1, later t3cl (PAD_CL front pad + end slack)
  float* Bf    = A + 4731136;        // t3, later t4
  float* offb  = Bf + 4718592;
  float* wt_r1 = offb + 1990656;
  float* wt_r2 = wt_r1 + 73728;
  float* wt_rs = wt_r2 + 147456;
  float* wt_off= wt_rs + 8192;
  float* wt_c2 = wt_off + 73728;
  float* wt_ds = wt_c2 + 16384;
  unsigned short* wpack = (unsigned short*)(wt_ds + 8192);  // 147456 bf16

  auto T = [&](const float* w, float* wt, int O, int KK, int Opad) {
    int n = KK * Opad;
    k_wtrans<<<dim3((n + 255) / 256), dim3(256), 0, stream>>>(w, wt, O, KK, Opad);
  };
  T(w_r1,  wt_r1, 128, 576, 128);
  T(w_r2,  wt_r2, 128, 1152, 128);
  T(w_rs,  wt_rs, 128, 64, 128);
  T(w_off, wt_off, 54, 1152, 64);
  T(w_c2,  wt_c2, 128, 128, 128);
  T(w_ds,  wt_ds, 128, 64, 128);
  k_wpack<<<dim3(576), dim3(256), 0, stream>>>(w_dcn, wpack);

  k_conv1 <<<dim3(48,16,4), dim3(96,2), 0, stream>>>(x, wt_r1, bn_r1, A);
  k_conv2 <<<dim3(48,16,4), dim3(96,2), 0, stream>>>(A, x, wt_r2, wt_rs, bn_r2, bn_rs, Bf);
  k_t3cl  <<<dim3(144,2,4), dim3(64,4), 0, stream>>>(Bf, A + PAD_CL);
  k_convoff<<<dim3(48,8,4), dim3(96,2), 0, stream>>>(Bf, wt_off, b_off, offb);
  k_dcn   <<<dim3(3,96,4), dim3(256), 0, stream>>>(A, offb, wpack, b_dcn, bn1, Bf);
  k_final <<<dim3(48,16,4), dim3(96,2), 0, stream>>>(Bf, x, wt_c2, wt_ds, bn2, bn_ds, out);
}

// Round 3
// 257.829 us; speedup vs baseline: 3.8616x; 2.5382x over previous
//
#include <hip/hip_runtime.h>
#include <hip/hip_bf16.h>
#include <cstdint>

#define EPS 1e-5f
#define NEG 0.1f

using bfrag = __attribute__((ext_vector_type(8))) short;   // 8 bf16
using f32x4 = __attribute__((ext_vector_type(4))) float;
typedef unsigned short ushort_t;

// geometry
constexpr int B_  = 4,  CIN = 64, H0 = 192, W0 = 192;
constexpr int C_  = 128, H_ = 96, W_ = 96;
constexpr int HW_ = H_ * W_;      // 9216
constexpr int HW0 = H0 * W0;      // 36864
constexpr int PAD2 = 97 * 128;    // 12416 elems: t3cl front/back pad for DCN gather
constexpr int VSTR = 1160;        // dcn val row stride (bf16): 16B-aligned, bank-spread

__device__ __forceinline__ ushort_t f2bf(float f) {
  unsigned u = __builtin_bit_cast(unsigned, f);
  u += 0x7fffu + ((u >> 16) & 1u);
  return (ushort_t)(u >> 16);
}
__device__ __forceinline__ float bf2f(ushort_t s) {
  return __builtin_bit_cast(float, (unsigned)s << 16);
}
__device__ __forceinline__ bfrag loadA(const ushort_t* p, bool ok) {
  bfrag z = {};
  if (ok) z = *(const bfrag*)p;
  return z;
}
__device__ __forceinline__ bfrag loadB(const ushort_t* p) {
  return *(const bfrag*)p;
}

#define MFMA4(A0, A1, B0, B1, ACC)                                             \
  ACC[0][0] = __builtin_amdgcn_mfma_f32_16x16x32_bf16(A0, B0, ACC[0][0], 0, 0, 0); \
  ACC[0][1] = __builtin_amdgcn_mfma_f32_16x16x32_bf16(A0, B1, ACC[0][1], 0, 0, 0); \
  ACC[1][0] = __builtin_amdgcn_mfma_f32_16x16x32_bf16(A1, B0, ACC[1][0], 0, 0, 0); \
  ACC[1][1] = __builtin_amdgcn_mfma_f32_16x16x32_bf16(A1, B1, ACC[1][1], 0, 0, 0);

// ---------------------------------------------------------------------------
// Weight packing.
// pack3: OIHW 3x3 -> bf16 [s][Opad][32], K order = tap*C + c (tap-major).
// ---------------------------------------------------------------------------
__global__ void k_pack3(const float* __restrict__ w, ushort_t* __restrict__ wp,
                        int O, int C, int Opad) {
  int idx = blockIdx.x * 256 + threadIdx.x;
  int e = idx & 31;
  int o = (idx >> 5) % Opad;
  int s = idx / (32 * Opad);
  int cq = C / 32;
  int tap = s / cq;
  int c = (s % cq) * 32 + e;
  wp[idx] = (o < O) ? f2bf(w[((size_t)o * C + c) * 9 + tap]) : (ushort_t)0;
}
// pack1: 1x1 conv [O][C] -> bf16 [s][Opad][32]
__global__ void k_pack1(const float* __restrict__ w, ushort_t* __restrict__ wp,
                        int O, int C, int Opad) {
  int idx = blockIdx.x * 256 + threadIdx.x;
  int e = idx & 31;
  int o = (idx >> 5) % Opad;
  int s = idx / (32 * Opad);
  wp[idx] = (o < O) ? f2bf(w[(size_t)o * C + s * 32 + e]) : (ushort_t)0;
}

// zero t3cl pads (poison safety: pads are read with weight-0 corners)
__global__ void k_zero(ushort_t* __restrict__ t3) {
  int idx = blockIdx.x * 256 + threadIdx.x;   // 24832 total
  if (idx < PAD2) t3[idx] = 0;
  else {
    int r = idx - PAD2;
    if (r < PAD2) t3[PAD2 + (size_t)B_ * HW_ * 128 + r] = 0;
  }
}

// ---------------------------------------------------------------------------
// x [4,64,192,192] fp32 NCHW -> xcl0 [4,192*192,64] bf16 NHWC
// ---------------------------------------------------------------------------
__global__ __launch_bounds__(256)
void k_xcl(const float* __restrict__ x, ushort_t* __restrict__ xcl) {
  __shared__ float tile[64][65];
  int tx = threadIdx.x, ty = threadIdx.y;
  int p0 = blockIdx.x * 64, b = blockIdx.z;
  const float* src = x + (size_t)b * CIN * HW0 + p0;
#pragma unroll
  for (int r = 0; r < 16; ++r) {
    int ch = r * 4 + ty;
    tile[ch][tx] = src[(size_t)ch * HW0 + tx];
  }
  __syncthreads();
  ushort_t* dst = xcl + ((size_t)b * HW0 + p0) * 64;
#pragma unroll
  for (int r = 0; r < 16; ++r) {
    int pp = r * 4 + ty;
    dst[(size_t)pp * 64 + tx] = f2bf(tile[tx][pp]);
  }
}

// ---------------------------------------------------------------------------
// K1: conv3x3 s2 p1 (64->128) + BN + LReLU.  xcl0 -> t1cl (NHWC bf16)
// out tile 32px x 128o, 4 waves
// ---------------------------------------------------------------------------
__global__ __launch_bounds__(256)
void k_conv1(const ushort_t* __restrict__ xcl, const ushort_t* __restrict__ wp,
             const float* __restrict__ bnp, ushort_t* __restrict__ t1cl) {
  int tid = threadIdx.x, lane = tid & 63, wv = tid >> 6;
  int lr = lane & 15, lq = lane >> 4, ob = wv * 32;
  int j0 = blockIdx.x * 32, i = blockIdx.y, b = blockIdx.z;
  f32x4 acc[2][2] = {};
  for (int tap = 0; tap < 9; ++tap) {
    int ky = tap / 3, kx = tap - 3 * ky;
    int y = 2 * i - 1 + ky;
    if ((unsigned)y >= 192u) continue;
    const ushort_t* rowp = xcl + (size_t)(b * 192 + y) * 192 * 64;
    int xa = 2 * (j0 + lr) - 1 + kx;
    int xb = 2 * (j0 + 16 + lr) - 1 + kx;
    bool oka = (unsigned)xa < 192u, okb = (unsigned)xb < 192u;
    const ushort_t* pa = rowp + (size_t)min(max(xa, 0), 191) * 64 + 8 * lq;
    const ushort_t* pb = rowp + (size_t)min(max(xb, 0), 191) * 64 + 8 * lq;
#pragma unroll
    for (int cq = 0; cq < 2; ++cq) {
      bfrag a0 = loadA(pa + cq * 32, oka);
      bfrag a1 = loadA(pb + cq * 32, okb);
      int s = tap * 2 + cq;
      const ushort_t* wb = wp + ((size_t)s * 128 + ob) * 32 + 8 * lq;
      bfrag b0 = loadB(wb + lr * 32);
      bfrag b1 = loadB(wb + (16 + lr) * 32);
      MFMA4(a0, a1, b0, b1, acc);
    }
  }
  ushort_t* dst = t1cl + ((size_t)(b * 96 + i) * 96 + j0) * 128;
#pragma unroll
  for (int nf = 0; nf < 2; ++nf) {
    int o = ob + nf * 16 + lr;
    float inv = bnp[o] * rsqrtf(bnp[384 + o] + EPS);
    float bb = bnp[128 + o] - bnp[256 + o] * inv;
#pragma unroll
    for (int mf = 0; mf < 2; ++mf)
#pragma unroll
      for (int jj = 0; jj < 4; ++jj) {
        int pix = mf * 16 + 4 * lq + jj;
        float r = acc[mf][nf][jj] * inv + bb;
        r = r >= 0.f ? r : NEG * r;
        dst[(size_t)pix * 128 + o] = f2bf(r);
      }
  }
}

// ---------------------------------------------------------------------------
// K2: conv3x3 s1 p1 (128->128)+BN  +  1x1 s2 shortcut (64->128)+BN, add, LReLU
// t1cl + xcl0 -> t3cl (NHWC bf16, PAD2 offset)
// ---------------------------------------------------------------------------
__global__ __launch_bounds__(256)
void k_conv2(const ushort_t* __restrict__ t1cl, const ushort_t* __restrict__ xcl,
             const ushort_t* __restrict__ wp2, const ushort_t* __restrict__ wprs,
             const float* __restrict__ bn2p, const float* __restrict__ bnsp,
             ushort_t* __restrict__ t3cl) {
  int tid = threadIdx.x, lane = tid & 63, wv = tid >> 6;
  int lr = lane & 15, lq = lane >> 4, ob = wv * 32;
  int j0 = blockIdx.x * 32, i = blockIdx.y, b = blockIdx.z;
  f32x4 acc[2][2] = {};
  f32x4 acs[2][2] = {};
  for (int tap = 0; tap < 9; ++tap) {
    int ky = tap / 3, kx = tap - 3 * ky;
    int y = i - 1 + ky;
    if ((unsigned)y >= 96u) continue;
    const ushort_t* rowp = t1cl + (size_t)(b * 96 + y) * 96 * 128;
    int xa = j0 + lr + kx - 1;
    int xb = xa + 16;
    bool oka = (unsigned)xa < 96u, okb = (unsigned)xb < 96u;
    const ushort_t* pa = rowp + (size_t)min(max(xa, 0), 95) * 128 + 8 * lq;
    const ushort_t* pb = rowp + (size_t)min(max(xb, 0), 95) * 128 + 8 * lq;
#pragma unroll
    for (int cq = 0; cq < 4; ++cq) {
      bfrag a0 = loadA(pa + cq * 32, oka);
      bfrag a1 = loadA(pb + cq * 32, okb);
      int s = tap * 4 + cq;
      const ushort_t* wb = wp2 + ((size_t)s * 128 + ob) * 32 + 8 * lq;
      bfrag b0 = loadB(wb + lr * 32);
      bfrag b1 = loadB(wb + (16 + lr) * 32);
      MFMA4(a0, a1, b0, b1, acc);
    }
  }
  {
    const ushort_t* rowp = xcl + (size_t)(b * 192 + 2 * i) * 192 * 64;
    const ushort_t* pa = rowp + (size_t)(2 * (j0 + lr)) * 64 + 8 * lq;
    const ushort_t* pb = rowp + (size_t)(2 * (j0 + 16 + lr)) * 64 + 8 * lq;
#pragma unroll
    for (int sq = 0; sq < 2; ++sq) {
      bfrag a0 = loadB(pa + sq * 32);
      bfrag a1 = loadB(pb + sq * 32);
      const ushort_t* wb = wprs + ((size_t)sq * 128 + ob) * 32 + 8 * lq;
      bfrag b0 = loadB(wb + lr * 32);
      bfrag b1 = loadB(wb + (16 + lr) * 32);
      MFMA4(a0, a1, b0, b1, acs);
    }
  }
  ushort_t* dst = t3cl + PAD2 + ((size_t)(b * 96 + i) * 96 + j0) * 128;
#pragma unroll
  for (int nf = 0; nf < 2; ++nf) {
    int o = ob + nf * 16 + lr;
    float i2 = bn2p[o] * rsqrtf(bn2p[384 + o] + EPS);
    float b2 = bn2p[128 + o] - bn2p[256 + o] * i2;
    float is = bnsp[o] * rsqrtf(bnsp[384 + o] + EPS);
    float bs = bnsp[128 + o] - bnsp[256 + o] * is;
#pragma unroll
    for (int mf = 0; mf < 2; ++mf)
#pragma unroll
      for (int jj = 0; jj < 4; ++jj) {
        int pix = mf * 16 + 4 * lq + jj;
        float h = acc[mf][nf][jj] * i2 + b2 + acs[mf][nf][jj] * is + bs;
        h = h >= 0.f ? h : NEG * h;
        dst[(size_t)pix * 128 + o] = f2bf(h);
      }
  }
}

// ---------------------------------------------------------------------------
// K3: conv3x3 s1 p1 (128->54, pad to 64) + bias -> offb_cl [4,9216,64] fp32
// out tile 32px x 64o, 2 waves (128 threads)
// ---------------------------------------------------------------------------
__global__ __launch_bounds__(128)
void k_convoff(const ushort_t* __restrict__ t3cl, const ushort_t* __restrict__ wp,
               const float* __restrict__ boff, float* __restrict__ offb) {
  int tid = threadIdx.x, lane = tid & 63, wv = tid >> 6;
  int lr = lane & 15, lq = lane >> 4, ob = wv * 32;
  int j0 = blockIdx.x * 32, i = blockIdx.y, b = blockIdx.z;
  const ushort_t* t3p = t3cl + PAD2;
  f32x4 acc[2][2] = {};
  for (int tap = 0; tap < 9; ++tap) {
    int ky = tap / 3, kx = tap - 3 * ky;
    int y = i - 1 + ky;
    if ((unsigned)y >= 96u) continue;
    const ushort_t* rowp = t3p + (size_t)(b * 96 + y) * 96 * 128;
    int xa = j0 + lr + kx - 1;
    int xb = xa + 16;
    bool oka = (unsigned)xa < 96u, okb = (unsigned)xb < 96u;
    const ushort_t* pa = rowp + (size_t)min(max(xa, 0), 95) * 128 + 8 * lq;
    const ushort_t* pb = rowp + (size_t)min(max(xb, 0), 95) * 128 + 8 * lq;
#pragma unroll
    for (int cq = 0; cq < 4; ++cq) {
      bfrag a0 = loadA(pa + cq * 32, oka);
      bfrag a1 = loadA(pb + cq * 32, okb);
      int s = tap * 4 + cq;
      const ushort_t* wb = wp + ((size_t)s * 64 + ob) * 32 + 8 * lq;
      bfrag b0 = loadB(wb + lr * 32);
      bfrag b1 = loadB(wb + (16 + lr) * 32);
      MFMA4(a0, a1, b0, b1, acc);
    }
  }
  float* dst = offb + ((size_t)b * HW_ + (size_t)i * W_ + j0) * 64;
#pragma unroll
  for (int nf = 0; nf < 2; ++nf) {
    int o = ob + nf * 16 + lr;
    float bias = (o < 54) ? boff[o] : 0.f;
#pragma unroll
    for (int mf = 0; mf < 2; ++mf)
#pragma unroll
      for (int jj = 0; jj < 4; ++jj) {
        int pix = mf * 16 + 4 * lq + jj;
        float v = (o < 54) ? acc[mf][nf][jj] + bias : 0.f;
        dst[(size_t)pix * 64 + o] = v;
      }
  }
}

// ---------------------------------------------------------------------------
// K4: DCNv2 sample + MFMA contract + bias + BN + LReLU -> t4cl (NHWC bf16)
// 16 pixels/block, 256 threads; val K-order = k*128 + cin
// ---------------------------------------------------------------------------
__global__ __launch_bounds__(256)
void k_dcn(const ushort_t* __restrict__ t3cl, const float* __restrict__ offb,
           const ushort_t* __restrict__ wp, const float* __restrict__ bdcn,
           const float* __restrict__ bnp, ushort_t* __restrict__ t4cl) {
  __shared__ ushort_t val[16 * VSTR];
  __shared__ ushort4 pre_w[288];
  __shared__ int pre_b[288];
  int tid = threadIdx.x;
  int j0 = blockIdx.x * 16, i = blockIdx.y, b = blockIdx.z;

  // phase 0: per-(pix, g, k) offset/mask/bilinear precompute
  for (int t = tid; t < 288; t += 256) {
    int pix = t / 18, gk = t - pix * 18;
    int g = gk / 9, k = gk - 9 * g;
    int ky = k / 3, kx = k - 3 * ky;
    int j = j0 + pix;
    const float* ob_ = offb + ((size_t)b * HW_ + (size_t)i * W_ + j) * 64;
    float dy = ob_[gk];
    float dx = ob_[18 + gk];
    float ml = ob_[36 + gk];
    float mk = 1.f / (1.f + __expf(-ml));
    float py = (float)(i - 1 + ky) + dy;
    float px = (float)(j - 1 + kx) + dx;
    float fy = floorf(py), fx = floorf(px);
    float wy = py - fy, wx = px - fx;
    int y0 = (int)fy, x0 = (int)fx;
    bool yv0 = (unsigned)y0 < 96u, yv1 = (unsigned)(y0 + 1) < 96u;
    bool xv0 = (unsigned)x0 < 96u, xv1 = (unsigned)(x0 + 1) < 96u;
    float w00 = (yv0 && xv0) ? (1.f - wy) * (1.f - wx) * mk : 0.f;
    float w01 = (yv0 && xv1) ? (1.f - wy) * wx * mk : 0.f;
    float w10 = (yv1 && xv0) ? wy * (1.f - wx) * mk : 0.f;
    float w11 = (yv1 && xv1) ? wy * wx * mk : 0.f;
    pre_b[t] = min(max(y0, -1), 95) * 96 + min(max(x0, -1), 95);
    pre_w[t] = make_ushort4(f2bf(w00), f2bf(w01), f2bf(w10), f2bf(w11));
  }
  __syncthreads();

  // phase 1: gather 16x1152 bf16 samples
  {
    int c = tid & 63, s4 = tid >> 6;
    const ushort_t* img0 = t3cl + PAD2 + (size_t)b * HW_ * 128 + c;
    for (int t = s4; t < 288; t += 4) {
      int pix = t / 18, gk = t - pix * 18;
      int g = gk / 9, k = gk - 9 * g;
      ushort4 w4 = pre_w[t];
      long base = pre_b[t];
      const ushort_t* tb = img0 + base * 128 + g * 64;
      float vv = bf2f(w4.x) * bf2f(tb[0]) + bf2f(w4.y) * bf2f(tb[128]) +
                 bf2f(w4.z) * bf2f(tb[96 * 128]) + bf2f(w4.w) * bf2f(tb[97 * 128]);
      val[pix * VSTR + k * 128 + g * 64 + c] = f2bf(vv);
    }
  }
  __syncthreads();

  // phase 2: MFMA out[16 pix][128 o], K=1152
  int lane = tid & 63, wv = tid >> 6;
  int lr = lane & 15, lq = lane >> 4, ob = wv * 32;
  f32x4 acc[2] = {};
  for (int s = 0; s < 36; ++s) {
    bfrag a0 = *(const bfrag*)&val[lr * VSTR + 32 * s + 8 * lq];
    const ushort_t* wb = wp + ((size_t)s * 128 + ob) * 32 + 8 * lq;
    bfrag b0 = loadB(wb + lr * 32);
    bfrag b1 = loadB(wb + (16 + lr) * 32);
    acc[0] = __builtin_amdgcn_mfma_f32_16x16x32_bf16(a0, b0, acc[0], 0, 0, 0);
    acc[1] = __builtin_amdgcn_mfma_f32_16x16x32_bf16(a0, b1, acc[1], 0, 0, 0);
  }

  // epilogue: bias + BN + LReLU, NHWC bf16 store
  ushort_t* dst = t4cl + ((size_t)(b * 96 + i) * 96 + j0) * 128;
#pragma unroll
  for (int nf = 0; nf < 2; ++nf) {
    int o = ob + nf * 16 + lr;
    float inv = bnp[o] * rsqrtf(bnp[384 + o] + EPS);
    float bb = bnp[128 + o] - bnp[256 + o] * inv;
    float bd = bdcn[o];
#pragma unroll
    for (int jj = 0; jj < 4; ++jj) {
      int pix = 4 * lq + jj;
      float r = (acc[nf][jj] + bd) * inv + bb;
      r = r >= 0.f ? r : NEG * r;
      dst[(size_t)pix * 128 + o] = f2bf(r);
    }
  }
}

// ---------------------------------------------------------------------------
// K5: 1x1 (128->128)+BN+LReLU  +  1x1 s2 residual (64->128)+BN -> out (NCHW fp32)
// ---------------------------------------------------------------------------
__global__ __launch_bounds__(256)
void k_final(const ushort_t* __restrict__ t4cl, const ushort_t* __restrict__ xcl,
             const ushort_t* __restrict__ wpc2, const ushort_t* __restrict__ wpds,
             const float* __restrict__ bn2p, const float* __restrict__ bndsp,
             float* __restrict__ outp) {
  __shared__ float ol[128 * 33];
  int tid = threadIdx.x, lane = tid & 63, wv = tid >> 6;
  int lr = lane & 15, lq = lane >> 4, ob = wv * 32;
  int j0 = blockIdx.x * 32, i = blockIdx.y, b = blockIdx.z;
  f32x4 acc[2][2] = {};
  f32x4 acs[2][2] = {};
  {
    const ushort_t* rowp = t4cl + ((size_t)(b * 96 + i) * 96 + j0) * 128;
#pragma unroll
    for (int s = 0; s < 4; ++s) {
      bfrag a0 = loadB(rowp + (size_t)lr * 128 + s * 32 + 8 * lq);
      bfrag a1 = loadB(rowp + (size_t)(16 + lr) * 128 + s * 32 + 8 * lq);
      const ushort_t* wb = wpc2 + ((size_t)s * 128 + ob) * 32 + 8 * lq;
      bfrag b0 = loadB(wb + lr * 32);
      bfrag b1 = loadB(wb + (16 + lr) * 32);
      MFMA4(a0, a1, b0, b1, acc);
    }
  }
  {
    const ushort_t* rowx = xcl + (size_t)(b * 192 + 2 * i) * 192 * 64;
    const ushort_t* pa = rowx + (size_t)(2 * (j0 + lr)) * 64 + 8 * lq;
    const ushort_t* pb = rowx + (size_t)(2 * (j0 + 16 + lr)) * 64 + 8 * lq;
#pragma unroll
    for (int s = 0; s < 2; ++s) {
      bfrag a0 = loadB(pa + s * 32);
      bfrag a1 = loadB(pb + s * 32);
      const ushort_t* wb = wpds + ((size_t)s * 128 + ob) * 32 + 8 * lq;
      bfrag b0 = loadB(wb + lr * 32);
      bfrag b1 = loadB(wb + (16 + lr) * 32);
      MFMA4(a0, a1, b0, b1, acs);
    }
  }
#pragma unroll
  for (int nf = 0; nf < 2; ++nf) {
    int o = ob + nf * 16 + lr;
    float i2 = bn2p[o] * rsqrtf(bn2p[384 + o] + EPS);
    float b2 = bn2p[128 + o] - bn2p[256 + o] * i2;
    float id = bndsp[o] * rsqrtf(bndsp[384 + o] + EPS);
    float bd = bndsp[128 + o] - bndsp[256 + o] * id;
#pragma unroll
    for (int mf = 0; mf < 2; ++mf)
#pragma unroll
      for (int jj = 0; jj < 4; ++jj) {
        int pix = mf * 16 + 4 * lq + jj;
        float h = acc[mf][nf][jj] * i2 + b2;
        h = h >= 0.f ? h : NEG * h;
        float res = acs[mf][nf][jj] * id + bd;
        ol[o * 33 + pix] = res + h;
      }
  }
  __syncthreads();
#pragma unroll
  for (int r = 0; r < 16; ++r) {
    int idx = r * 256 + tid;
    int o = idx >> 5, pix = idx & 31;
    outp[((size_t)(b * C_ + o) * H_ + i) * W_ + j0 + pix] = ol[o * 33 + pix];
  }
}

// ---------------------------------------------------------------------------
extern "C" void kernel_launch(void* const* d_in, const int* in_sizes, int n_in,
                              void* d_out, int out_size, void* d_ws, size_t ws_size,
                              hipStream_t stream) {
  const float* x     = (const float*)d_in[0];
  const float* w_r1  = (const float*)d_in[1];
  const float* bn_r1 = (const float*)d_in[2];
  const float* w_r2  = (const float*)d_in[3];
  const float* bn_r2 = (const float*)d_in[4];
  const float* w_rs  = (const float*)d_in[5];
  const float* bn_rs = (const float*)d_in[6];
  const float* w_off = (const float*)d_in[7];
  const float* b_off = (const float*)d_in[8];
  const float* w_dcn = (const float*)d_in[9];
  const float* b_dcn = (const float*)d_in[10];
  const float* bn1   = (const float*)d_in[11];
  const float* w_c2  = (const float*)d_in[12];
  const float* bn2   = (const float*)d_in[13];
  const float* w_ds  = (const float*)d_in[14];
  const float* bn_ds = (const float*)d_in[15];
  float* out = (float*)d_out;

  // workspace layout (ushort elems); total ~38.8 MB
  ushort_t* base  = (ushort_t*)d_ws;
  ushort_t* xcl0  = base;                        // 9437184
  ushort_t* t1cl  = base + 9437184;              // 4718592 (later aliased offb/t4cl)
  ushort_t* t3cl  = base + 14155776;             // 12416 + 4718592 + 12416
  ushort_t* wp_r1 = base + 18899200;             // 73728
  ushort_t* wp_r2 = wp_r1 + 73728;               // 147456
  ushort_t* wp_off= wp_r2 + 147456;              // 73728 (Opad=64)
  ushort_t* wp_dcn= wp_off + 73728;              // 147456
  ushort_t* wp_rs = wp_dcn + 147456;             // 8192
  ushort_t* wp_c2 = wp_rs + 8192;                // 16384
  ushort_t* wp_ds = wp_c2 + 16384;               // 8192
  float*    offb  = (float*)t1cl;                // 2359296 fp32 == t1cl bytes
  ushort_t* t4cl  = t1cl;                        // aliases offb (per-pixel RAW safe)

  k_pack3<<<288, 256, 0, stream>>>(w_r1,  wp_r1, 128, 64, 128);
  k_pack3<<<576, 256, 0, stream>>>(w_r2,  wp_r2, 128, 128, 128);
  k_pack3<<<288, 256, 0, stream>>>(w_off, wp_off, 54, 128, 64);
  k_pack3<<<576, 256, 0, stream>>>(w_dcn, wp_dcn, 128, 128, 128);
  k_pack1<<<32,  256, 0, stream>>>(w_rs,  wp_rs, 128, 64, 128);
  k_pack1<<<64,  256, 0, stream>>>(w_c2,  wp_c2, 128, 128, 128);
  k_pack1<<<32,  256, 0, stream>>>(w_ds,  wp_ds, 128, 64, 128);
  k_zero <<<97,  256, 0, stream>>>(t3cl);

  k_xcl    <<<dim3(576, 1, 4), dim3(64, 4), 0, stream>>>(x, xcl0);
  k_conv1  <<<dim3(3, 96, 4), 256, 0, stream>>>(xcl0, wp_r1, bn_r1, t1cl);
  k_conv2  <<<dim3(3, 96, 4), 256, 0, stream>>>(t1cl, xcl0, wp_r2, wp_rs, bn_r2, bn_rs, t3cl);
  k_convoff<<<dim3(3, 96, 4), 128, 0, stream>>>(t3cl, wp_off, b_off, offb);
  k_dcn    <<<dim3(6, 96, 4), 256, 0, stream>>>(t3cl, offb, wp_dcn, b_dcn, bn1, t4cl);
  k_final  <<<dim3(3, 96, 4), 256, 0, stream>>>(t4cl, xcl0, wp_c2, wp_ds, bn2, bn_ds, out);
}

// Round 4
// 219.856 us; speedup vs baseline: 4.5286x; 1.1727x over previous
//
#include <hip/hip_runtime.h>
#include <hip/hip_bf16.h>
#include <cstdint>

#define EPS 1e-5f
#define NEG 0.1f

using bfrag = __attribute__((ext_vector_type(8))) short;   // 8 bf16
using f32x4 = __attribute__((ext_vector_type(4))) float;
typedef unsigned short ushort_t;

// geometry
constexpr int B_  = 4,  CIN = 64, H0 = 192, W0 = 192;
constexpr int C_  = 128, H_ = 96, W_ = 96;
constexpr int HW_ = H_ * W_;      // 9216
constexpr int HW0 = H0 * W0;      // 36864
constexpr int PAD2 = 97 * 128;    // 12416 elems: t3cl front/back pad for DCN gather
constexpr int VSTR = 1160;        // dcn val row stride (bf16): 16B-aligned

__device__ __forceinline__ ushort_t f2bf(float f) {
  unsigned u = __builtin_bit_cast(unsigned, f);
  u += 0x7fffu + ((u >> 16) & 1u);
  return (ushort_t)(u >> 16);
}
__device__ __forceinline__ float bf2f(ushort_t s) {
  return __builtin_bit_cast(float, (unsigned)s << 16);
}
__device__ __forceinline__ float loF(unsigned d) {          // low bf16 -> f32
  return __builtin_bit_cast(float, d << 16);
}
__device__ __forceinline__ float hiF(unsigned d) {          // high bf16 -> f32
  return __builtin_bit_cast(float, d & 0xFFFF0000u);
}
__device__ __forceinline__ bfrag loadA(const ushort_t* p, bool ok) {
  bfrag z = {};
  if (ok) z = *(const bfrag*)p;
  return z;
}
__device__ __forceinline__ bfrag loadB(const ushort_t* p) {
  return *(const bfrag*)p;
}

#define MFMA4(A0, A1, B0, B1, ACC)                                             \
  ACC[0][0] = __builtin_amdgcn_mfma_f32_16x16x32_bf16(A0, B0, ACC[0][0], 0, 0, 0); \
  ACC[0][1] = __builtin_amdgcn_mfma_f32_16x16x32_bf16(A0, B1, ACC[0][1], 0, 0, 0); \
  ACC[1][0] = __builtin_amdgcn_mfma_f32_16x16x32_bf16(A1, B0, ACC[1][0], 0, 0, 0); \
  ACC[1][1] = __builtin_amdgcn_mfma_f32_16x16x32_bf16(A1, B1, ACC[1][1], 0, 0, 0);

// ---------------------------------------------------------------------------
// k_prep: ALL weight packing + t3cl pad zeroing in ONE launch (1953 blocks).
// pack3: OIHW 3x3 -> bf16 [s][Opad][32], K order = tap*C + c (tap-major).
// pack1: 1x1 [O][C] -> bf16 [s][Opad][32].
// ---------------------------------------------------------------------------
__global__ __launch_bounds__(256)
void k_prep(const float* __restrict__ w_r1, const float* __restrict__ w_r2,
            const float* __restrict__ w_off, const float* __restrict__ w_dcn,
            const float* __restrict__ w_rs, const float* __restrict__ w_c2,
            const float* __restrict__ w_ds,
            ushort_t* __restrict__ wp_r1, ushort_t* __restrict__ wp_r2,
            ushort_t* __restrict__ wp_off, ushort_t* __restrict__ wp_dcn,
            ushort_t* __restrict__ wp_rs, ushort_t* __restrict__ wp_c2,
            ushort_t* __restrict__ wp_ds, ushort_t* __restrict__ t3cl) {
  int bi = blockIdx.x;
  auto pack3 = [&](const float* w, ushort_t* wp, int O, int C, int Opad, int b0) {
    int idx = (bi - b0) * 256 + (int)threadIdx.x;
    int e = idx & 31, o = (idx >> 5) % Opad, s = idx / (32 * Opad);
    int cq = C / 32, tap = s / cq, c = (s % cq) * 32 + e;
    wp[idx] = (o < O) ? f2bf(w[((size_t)o * C + c) * 9 + tap]) : (ushort_t)0;
  };
  auto pack1 = [&](const float* w, ushort_t* wp, int O, int C, int Opad, int b0) {
    int idx = (bi - b0) * 256 + (int)threadIdx.x;
    int e = idx & 31, o = (idx >> 5) % Opad, s = idx / (32 * Opad);
    wp[idx] = (o < O) ? f2bf(w[(size_t)o * C + s * 32 + e]) : (ushort_t)0;
  };
  if      (bi <  288) pack3(w_r1,  wp_r1, 128,  64, 128, 0);
  else if (bi <  864) pack3(w_r2,  wp_r2, 128, 128, 128, 288);
  else if (bi < 1152) pack3(w_off, wp_off, 54, 128,  64, 864);
  else if (bi < 1728) pack3(w_dcn, wp_dcn, 128, 128, 128, 1152);
  else if (bi < 1760) pack1(w_rs,  wp_rs, 128,  64, 128, 1728);
  else if (bi < 1824) pack1(w_c2,  wp_c2, 128, 128, 128, 1760);
  else if (bi < 1856) pack1(w_ds,  wp_ds, 128,  64, 128, 1824);
  else {
    int idx = (bi - 1856) * 256 + (int)threadIdx.x;   // 24832 total
    if (idx < PAD2) t3cl[idx] = 0;
    else {
      int r = idx - PAD2;
      if (r < PAD2) t3cl[PAD2 + (size_t)B_ * HW_ * 128 + r] = 0;
    }
  }
}

// ---------------------------------------------------------------------------
// x [4,64,192,192] fp32 NCHW -> xcl0 [4,192*192,64] bf16 NHWC
// ---------------------------------------------------------------------------
__global__ __launch_bounds__(256)
void k_xcl(const float* __restrict__ x, ushort_t* __restrict__ xcl) {
  __shared__ float tile[64][65];
  int tx = threadIdx.x, ty = threadIdx.y;
  int p0 = blockIdx.x * 64, b = blockIdx.z;
  const float* src = x + (size_t)b * CIN * HW0 + p0;
#pragma unroll
  for (int r = 0; r < 16; ++r) {
    int ch = r * 4 + ty;
    tile[ch][tx] = src[(size_t)ch * HW0 + tx];
  }
  __syncthreads();
  ushort_t* dst = xcl + ((size_t)b * HW0 + p0) * 64;
#pragma unroll
  for (int r = 0; r < 16; ++r) {
    int pp = r * 4 + ty;
    dst[(size_t)pp * 64 + tx] = f2bf(tile[tx][pp]);
  }
}

// ---------------------------------------------------------------------------
// K1: conv3x3 s2 p1 (64->128) + BN + LReLU.  xcl0 -> t1cl (NHWC bf16)
// ---------------------------------------------------------------------------
__global__ __launch_bounds__(256)
void k_conv1(const ushort_t* __restrict__ xcl, const ushort_t* __restrict__ wp,
             const float* __restrict__ bnp, ushort_t* __restrict__ t1cl) {
  int tid = threadIdx.x, lane = tid & 63, wv = tid >> 6;
  int lr = lane & 15, lq = lane >> 4, ob = wv * 32;
  int j0 = blockIdx.x * 32, i = blockIdx.y, b = blockIdx.z;
  f32x4 acc[2][2] = {};
  for (int tap = 0; tap < 9; ++tap) {
    int ky = tap / 3, kx = tap - 3 * ky;
    int y = 2 * i - 1 + ky;
    if ((unsigned)y >= 192u) continue;
    const ushort_t* rowp = xcl + (size_t)(b * 192 + y) * 192 * 64;
    int xa = 2 * (j0 + lr) - 1 + kx;
    int xb = 2 * (j0 + 16 + lr) - 1 + kx;
    bool oka = (unsigned)xa < 192u, okb = (unsigned)xb < 192u;
    const ushort_t* pa = rowp + (size_t)min(max(xa, 0), 191) * 64 + 8 * lq;
    const ushort_t* pb = rowp + (size_t)min(max(xb, 0), 191) * 64 + 8 * lq;
#pragma unroll
    for (int cq = 0; cq < 2; ++cq) {
      bfrag a0 = loadA(pa + cq * 32, oka);
      bfrag a1 = loadA(pb + cq * 32, okb);
      int s = tap * 2 + cq;
      const ushort_t* wb = wp + ((size_t)s * 128 + ob) * 32 + 8 * lq;
      bfrag b0 = loadB(wb + lr * 32);
      bfrag b1 = loadB(wb + (16 + lr) * 32);
      MFMA4(a0, a1, b0, b1, acc);
    }
  }
  ushort_t* dst = t1cl + ((size_t)(b * 96 + i) * 96 + j0) * 128;
#pragma unroll
  for (int nf = 0; nf < 2; ++nf) {
    int o = ob + nf * 16 + lr;
    float inv = bnp[o] * rsqrtf(bnp[384 + o] + EPS);
    float bb = bnp[128 + o] - bnp[256 + o] * inv;
#pragma unroll
    for (int mf = 0; mf < 2; ++mf)
#pragma unroll
      for (int jj = 0; jj < 4; ++jj) {
        int pix = mf * 16 + 4 * lq + jj;
        float r = acc[mf][nf][jj] * inv + bb;
        r = r >= 0.f ? r : NEG * r;
        dst[(size_t)pix * 128 + o] = f2bf(r);
      }
  }
}

// ---------------------------------------------------------------------------
// K2: conv3x3 s1 p1 (128->128)+BN  +  1x1 s2 shortcut (64->128)+BN, add, LReLU
// ---------------------------------------------------------------------------
__global__ __launch_bounds__(256)
void k_conv2(const ushort_t* __restrict__ t1cl, const ushort_t* __restrict__ xcl,
             const ushort_t* __restrict__ wp2, const ushort_t* __restrict__ wprs,
             const float* __restrict__ bn2p, const float* __restrict__ bnsp,
             ushort_t* __restrict__ t3cl) {
  int tid = threadIdx.x, lane = tid & 63, wv = tid >> 6;
  int lr = lane & 15, lq = lane >> 4, ob = wv * 32;
  int j0 = blockIdx.x * 32, i = blockIdx.y, b = blockIdx.z;
  f32x4 acc[2][2] = {};
  f32x4 acs[2][2] = {};
  for (int tap = 0; tap < 9; ++tap) {
    int ky = tap / 3, kx = tap - 3 * ky;
    int y = i - 1 + ky;
    if ((unsigned)y >= 96u) continue;
    const ushort_t* rowp = t1cl + (size_t)(b * 96 + y) * 96 * 128;
    int xa = j0 + lr + kx - 1;
    int xb = xa + 16;
    bool oka = (unsigned)xa < 96u, okb = (unsigned)xb < 96u;
    const ushort_t* pa = rowp + (size_t)min(max(xa, 0), 95) * 128 + 8 * lq;
    const ushort_t* pb = rowp + (size_t)min(max(xb, 0), 95) * 128 + 8 * lq;
#pragma unroll
    for (int cq = 0; cq < 4; ++cq) {
      bfrag a0 = loadA(pa + cq * 32, oka);
      bfrag a1 = loadA(pb + cq * 32, okb);
      int s = tap * 4 + cq;
      const ushort_t* wb = wp2 + ((size_t)s * 128 + ob) * 32 + 8 * lq;
      bfrag b0 = loadB(wb + lr * 32);
      bfrag b1 = loadB(wb + (16 + lr) * 32);
      MFMA4(a0, a1, b0, b1, acc);
    }
  }
  {
    const ushort_t* rowp = xcl + (size_t)(b * 192 + 2 * i) * 192 * 64;
    const ushort_t* pa = rowp + (size_t)(2 * (j0 + lr)) * 64 + 8 * lq;
    const ushort_t* pb = rowp + (size_t)(2 * (j0 + 16 + lr)) * 64 + 8 * lq;
#pragma unroll
    for (int sq = 0; sq < 2; ++sq) {
      bfrag a0 = loadB(pa + sq * 32);
      bfrag a1 = loadB(pb + sq * 32);
      const ushort_t* wb = wprs + ((size_t)sq * 128 + ob) * 32 + 8 * lq;
      bfrag b0 = loadB(wb + lr * 32);
      bfrag b1 = loadB(wb + (16 + lr) * 32);
      MFMA4(a0, a1, b0, b1, acs);
    }
  }
  ushort_t* dst = t3cl + PAD2 + ((size_t)(b * 96 + i) * 96 + j0) * 128;
#pragma unroll
  for (int nf = 0; nf < 2; ++nf) {
    int o = ob + nf * 16 + lr;
    float i2 = bn2p[o] * rsqrtf(bn2p[384 + o] + EPS);
    float b2 = bn2p[128 + o] - bn2p[256 + o] * i2;
    float is = bnsp[o] * rsqrtf(bnsp[384 + o] + EPS);
    float bs = bnsp[128 + o] - bnsp[256 + o] * is;
#pragma unroll
    for (int mf = 0; mf < 2; ++mf)
#pragma unroll
      for (int jj = 0; jj < 4; ++jj) {
        int pix = mf * 16 + 4 * lq + jj;
        float h = acc[mf][nf][jj] * i2 + b2 + acs[mf][nf][jj] * is + bs;
        h = h >= 0.f ? h : NEG * h;
        dst[(size_t)pix * 128 + o] = f2bf(h);
      }
  }
}

// ---------------------------------------------------------------------------
// K3: conv3x3 s1 p1 (128->54, pad to 64) + bias -> offb_cl [4,9216,64] fp32
// ---------------------------------------------------------------------------
__global__ __launch_bounds__(128)
void k_convoff(const ushort_t* __restrict__ t3cl, const ushort_t* __restrict__ wp,
               const float* __restrict__ boff, float* __restrict__ offb) {
  int tid = threadIdx.x, lane = tid & 63, wv = tid >> 6;
  int lr = lane & 15, lq = lane >> 4, ob = wv * 32;
  int j0 = blockIdx.x * 32, i = blockIdx.y, b = blockIdx.z;
  const ushort_t* t3p = t3cl + PAD2;
  f32x4 acc[2][2] = {};
  for (int tap = 0; tap < 9; ++tap) {
    int ky = tap / 3, kx = tap - 3 * ky;
    int y = i - 1 + ky;
    if ((unsigned)y >= 96u) continue;
    const ushort_t* rowp = t3p + (size_t)(b * 96 + y) * 96 * 128;
    int xa = j0 + lr + kx - 1;
    int xb = xa + 16;
    bool oka = (unsigned)xa < 96u, okb = (unsigned)xb < 96u;
    const ushort_t* pa = rowp + (size_t)min(max(xa, 0), 95) * 128 + 8 * lq;
    const ushort_t* pb = rowp + (size_t)min(max(xb, 0), 95) * 128 + 8 * lq;
#pragma unroll
    for (int cq = 0; cq < 4; ++cq) {
      bfrag a0 = loadA(pa + cq * 32, oka);
      bfrag a1 = loadA(pb + cq * 32, okb);
      int s = tap * 4 + cq;
      const ushort_t* wb = wp + ((size_t)s * 64 + ob) * 32 + 8 * lq;
      bfrag b0 = loadB(wb + lr * 32);
      bfrag b1 = loadB(wb + (16 + lr) * 32);
      MFMA4(a0, a1, b0, b1, acc);
    }
  }
  float* dst = offb + ((size_t)b * HW_ + (size_t)i * W_ + j0) * 64;
#pragma unroll
  for (int nf = 0; nf < 2; ++nf) {
    int o = ob + nf * 16 + lr;
    float bias = (o < 54) ? boff[o] : 0.f;
#pragma unroll
    for (int mf = 0; mf < 2; ++mf)
#pragma unroll
      for (int jj = 0; jj < 4; ++jj) {
        int pix = mf * 16 + 4 * lq + jj;
        float v = (o < 54) ? acc[mf][nf][jj] + bias : 0.f;
        dst[(size_t)pix * 64 + o] = v;
      }
  }
}

// ---------------------------------------------------------------------------
// K4: DCNv2 — byte-offset precompute, 2-ch/lane dword gather, MFMA contract
// 16 pixels/block, 256 threads; val K-order = k*128 + (g*64+c)
// ---------------------------------------------------------------------------
__global__ __launch_bounds__(256)
void k_dcn(const ushort_t* __restrict__ t3cl, const float* __restrict__ offb,
           const ushort_t* __restrict__ wp, const float* __restrict__ bdcn,
           const float* __restrict__ bnp, ushort_t* __restrict__ t4cl) {
  __shared__ ushort_t val[16 * VSTR];    // 37120 B
  __shared__ int2  pre_b2[288];          // .x = gather byte off, .y = LDS byte off
  __shared__ uint2 pre_w2[288];          // packed bf16 (w00,w01),(w10,w11)
  int tid = threadIdx.x;
  int j0 = blockIdx.x * 16, i = blockIdx.y, b = blockIdx.z;

  // phase 0: per-(pix,g,k) precompute -> byte offsets + packed weights
  for (int t = tid; t < 288; t += 256) {
    int pix = t / 18, gk = t - pix * 18;
    int g = gk / 9, k = gk - 9 * g;
    int ky = k / 3, kx = k - 3 * ky;
    int j = j0 + pix;
    const float* ob_ = offb + ((size_t)b * HW_ + (size_t)i * W_ + j) * 64;
    float dy = ob_[gk];
    float dx = ob_[18 + gk];
    float ml = ob_[36 + gk];
    float mk = 1.f / (1.f + __expf(-ml));
    float py = (float)(i - 1 + ky) + dy;
    float px = (float)(j - 1 + kx) + dx;
    float fy = floorf(py), fx = floorf(px);
    float wy = py - fy, wx = px - fx;
    int y0 = (int)fy, x0 = (int)fx;
    bool yv0 = (unsigned)y0 < 96u, yv1 = (unsigned)(y0 + 1) < 96u;
    bool xv0 = (unsigned)x0 < 96u, xv1 = (unsigned)(x0 + 1) < 96u;
    float w00 = (yv0 && xv0) ? (1.f - wy) * (1.f - wx) * mk : 0.f;
    float w01 = (yv0 && xv1) ? (1.f - wy) * wx * mk : 0.f;
    float w10 = (yv1 && xv0) ? wy * (1.f - wx) * mk : 0.f;
    float w11 = (yv1 && xv1) ? wy * wx * mk : 0.f;
    int yb = min(max(y0, -1), 95), xb = min(max(x0, -1), 95);
    pre_b2[t] = make_int2(((yb * 96 + xb) * 128 + g * 64) * 2,
                          (k * 128 + g * 64) * 2);
    pre_w2[t] = make_uint2((unsigned)f2bf(w00) | ((unsigned)f2bf(w01) << 16),
                           (unsigned)f2bf(w10) | ((unsigned)f2bf(w11) << 16));
  }
  __syncthreads();

  // phase 1: gather; each 32-lane half does one (pix,gk); 2 channels per lane
  {
    int wv = tid >> 6;                 // wave 0..3
    int half = (tid >> 5) & 1;         // which gk of the pair
    int c4 = (tid & 31) * 4;           // channel-pair byte offset
    const char* imgb = (const char*)(t3cl + PAD2 + (size_t)b * HW_ * 128) + c4;
#pragma unroll
    for (int pq = 0; pq < 4; ++pq) {
      int pix = wv * 4 + pq;
      char* vrow = (char*)val + pix * (VSTR * 2) + c4;
#pragma unroll
      for (int gk2 = 0; gk2 < 18; gk2 += 2) {
        int idx = pix * 18 + gk2 + half;
        int2 bb = pre_b2[idx];
        uint2 ww = pre_w2[idx];
        const char* pA = imgb + bb.x;
        const char* pB = pA + 96 * 256;
        unsigned d00 = *(const unsigned*)(pA);
        unsigned d01 = *(const unsigned*)(pA + 256);
        unsigned d10 = *(const unsigned*)(pB);
        unsigned d11 = *(const unsigned*)(pB + 256);
        float w00 = loF(ww.x), w01 = hiF(ww.x);
        float w10 = loF(ww.y), w11 = hiF(ww.y);
        float slo = loF(d00) * w00 + loF(d01) * w01 + loF(d10) * w10 + loF(d11) * w11;
        float shi = hiF(d00) * w00 + hiF(d01) * w01 + hiF(d10) * w10 + hiF(d11) * w11;
        unsigned u0 = __builtin_bit_cast(unsigned, slo) + 0x8000u;
        unsigned u1 = __builtin_bit_cast(unsigned, shi) + 0x8000u;
        *(unsigned*)(vrow + bb.y) = __builtin_amdgcn_perm(u1, u0, 0x07060302u);
      }
    }
  }
  __syncthreads();

  // phase 2: MFMA out[16 pix][128 o], K=1152
  int lane = tid & 63, wv = tid >> 6;
  int lr = lane & 15, lq = lane >> 4, ob = wv * 32;
  f32x4 acc[2] = {};
  for (int s = 0; s < 36; ++s) {
    bfrag a0 = *(const bfrag*)&val[lr * VSTR + 32 * s + 8 * lq];
    const ushort_t* wb = wp + ((size_t)s * 128 + ob) * 32 + 8 * lq;
    bfrag b0 = loadB(wb + lr * 32);
    bfrag b1 = loadB(wb + (16 + lr) * 32);
    acc[0] = __builtin_amdgcn_mfma_f32_16x16x32_bf16(a0, b0, acc[0], 0, 0, 0);
    acc[1] = __builtin_amdgcn_mfma_f32_16x16x32_bf16(a0, b1, acc[1], 0, 0, 0);
  }

  // epilogue: bias + BN + LReLU, NHWC bf16 store
  ushort_t* dst = t4cl + ((size_t)(b * 96 + i) * 96 + j0) * 128;
#pragma unroll
  for (int nf = 0; nf < 2; ++nf) {
    int o = ob + nf * 16 + lr;
    float inv = bnp[o] * rsqrtf(bnp[384 + o] + EPS);
    float bb = bnp[128 + o] - bnp[256 + o] * inv;
    float bd = bdcn[o];
#pragma unroll
    for (int jj = 0; jj < 4; ++jj) {
      int pix = 4 * lq + jj;
      float r = (acc[nf][jj] + bd) * inv + bb;
      r = r >= 0.f ? r : NEG * r;
      dst[(size_t)pix * 128 + o] = f2bf(r);
    }
  }
}

// ---------------------------------------------------------------------------
// K5: 1x1 (128->128)+BN+LReLU  +  1x1 s2 residual (64->128)+BN -> out (NCHW fp32)
// ---------------------------------------------------------------------------
__global__ __launch_bounds__(256)
void k_final(const ushort_t* __restrict__ t4cl, const ushort_t* __restrict__ xcl,
             const ushort_t* __restrict__ wpc2, const ushort_t* __restrict__ wpds,
             const float* __restrict__ bn2p, const float* __restrict__ bndsp,
             float* __restrict__ outp) {
  __shared__ float ol[128 * 33];
  int tid = threadIdx.x, lane = tid & 63, wv = tid >> 6;
  int lr = lane & 15, lq = lane >> 4, ob = wv * 32;
  int j0 = blockIdx.x * 32, i = blockIdx.y, b = blockIdx.z;
  f32x4 acc[2][2] = {};
  f32x4 acs[2][2] = {};
  {
    const ushort_t* rowp = t4cl + ((size_t)(b * 96 + i) * 96 + j0) * 128;
#pragma unroll
    for (int s = 0; s < 4; ++s) {
      bfrag a0 = loadB(rowp + (size_t)lr * 128 + s * 32 + 8 * lq);
      bfrag a1 = loadB(rowp + (size_t)(16 + lr) * 128 + s * 32 + 8 * lq);
      const ushort_t* wb = wpc2 + ((size_t)s * 128 + ob) * 32 + 8 * lq;
      bfrag b0 = loadB(wb + lr * 32);
      bfrag b1 = loadB(wb + (16 + lr) * 32);
      MFMA4(a0, a1, b0, b1, acc);
    }
  }
  {
    const ushort_t* rowx = xcl + (size_t)(b * 192 + 2 * i) * 192 * 64;
    const ushort_t* pa = rowx + (size_t)(2 * (j0 + lr)) * 64 + 8 * lq;
    const ushort_t* pb = rowx + (size_t)(2 * (j0 + 16 + lr)) * 64 + 8 * lq;
#pragma unroll
    for (int s = 0; s < 2; ++s) {
      bfrag a0 = loadB(pa + s * 32);
      bfrag a1 = loadB(pb + s * 32);
      const ushort_t* wb = wpds + ((size_t)s * 128 + ob) * 32 + 8 * lq;
      bfrag b0 = loadB(wb + lr * 32);
      bfrag b1 = loadB(wb + (16 + lr) * 32);
      MFMA4(a0, a1, b0, b1, acs);
    }
  }
#pragma unroll
  for (int nf = 0; nf < 2; ++nf) {
    int o = ob + nf * 16 + lr;
    float i2 = bn2p[o] * rsqrtf(bn2p[384 + o] + EPS);
    float b2 = bn2p[128 + o] - bn2p[256 + o] * i2;
    float id = bndsp[o] * rsqrtf(bndsp[384 + o] + EPS);
    float bd = bndsp[128 + o] - bndsp[256 + o] * id;
#pragma unroll
    for (int mf = 0; mf < 2; ++mf)
#pragma unroll
      for (int jj = 0; jj < 4; ++jj) {
        int pix = mf * 16 + 4 * lq + jj;
        float h = acc[mf][nf][jj] * i2 + b2;
        h = h >= 0.f ? h : NEG * h;
        float res = acs[mf][nf][jj] * id + bd;
        ol[o * 33 + pix] = res + h;
      }
  }
  __syncthreads();
#pragma unroll
  for (int r = 0; r < 16; ++r) {
    int idx = r * 256 + tid;
    int o = idx >> 5, pix = idx & 31;
    outp[((size_t)(b * C_ + o) * H_ + i) * W_ + j0 + pix] = ol[o * 33 + pix];
  }
}

// ---------------------------------------------------------------------------
extern "C" void kernel_launch(void* const* d_in, const int* in_sizes, int n_in,
                              void* d_out, int out_size, void* d_ws, size_t ws_size,
                              hipStream_t stream) {
  const float* x     = (const float*)d_in[0];
  const float* w_r1  = (const float*)d_in[1];
  const float* bn_r1 = (const float*)d_in[2];
  const float* w_r2  = (const float*)d_in[3];
  const float* bn_r2 = (const float*)d_in[4];
  const float* w_rs  = (const float*)d_in[5];
  const float* bn_rs = (const float*)d_in[6];
  const float* w_off = (const float*)d_in[7];
  const float* b_off = (const float*)d_in[8];
  const float* w_dcn = (const float*)d_in[9];
  const float* b_dcn = (const float*)d_in[10];
  const float* bn1   = (const float*)d_in[11];
  const float* w_c2  = (const float*)d_in[12];
  const float* bn2   = (const float*)d_in[13];
  const float* w_ds  = (const float*)d_in[14];
  const float* bn_ds = (const float*)d_in[15];
  float* out = (float*)d_out;

  // workspace layout (ushort elems); total ~38.8 MB
  ushort_t* base  = (ushort_t*)d_ws;
  ushort_t* xcl0  = base;                        // 9437184
  ushort_t* t1cl  = base + 9437184;              // 4718592 (later aliased offb/t4cl)
  ushort_t* t3cl  = base + 14155776;             // 12416 + 4718592 + 12416
  ushort_t* wp_r1 = base + 18899200;             // 73728
  ushort_t* wp_r2 = wp_r1 + 73728;               // 147456
  ushort_t* wp_off= wp_r2 + 147456;              // 73728 (Opad=64)
  ushort_t* wp_dcn= wp_off + 73728;              // 147456
  ushort_t* wp_rs = wp_dcn + 147456;             // 8192
  ushort_t* wp_c2 = wp_rs + 8192;                // 16384
  ushort_t* wp_ds = wp_c2 + 16384;               // 8192
  float*    offb  = (float*)t1cl;                // 2359296 fp32 == t1cl bytes
  ushort_t* t4cl  = t1cl;                        // aliases offb (per-pixel RAW safe)

  k_prep<<<1953, 256, 0, stream>>>(w_r1, w_r2, w_off, w_dcn, w_rs, w_c2, w_ds,
                                   wp_r1, wp_r2, wp_off, wp_dcn, wp_rs, wp_c2,
                                   wp_ds, t3cl);

  k_xcl    <<<dim3(576, 1, 4), dim3(64, 4), 0, stream>>>(x, xcl0);
  k_conv1  <<<dim3(3, 96, 4), 256, 0, stream>>>(xcl0, wp_r1, bn_r1, t1cl);
  k_conv2  <<<dim3(3, 96, 4), 256, 0, stream>>>(t1cl, xcl0, wp_r2, wp_rs, bn_r2, bn_rs, t3cl);
  k_convoff<<<dim3(3, 96, 4), 128, 0, stream>>>(t3cl, wp_off, b_off, offb);
  k_dcn    <<<dim3(6, 96, 4), 256, 0, stream>>>(t3cl, offb, wp_dcn, b_dcn, bn1, t4cl);
  k_final  <<<dim3(3, 96, 4), 256, 0, stream>>>(t4cl, xcl0, wp_c2, wp_ds, bn2, bn_ds, out);
}